// Round 2
// baseline (149.567 us; speedup 1.0000x reference)
//
#include <hip/hip_runtime.h>
#include <hip/hip_bf16.h>

#define Bn 8192
#define Dn 256
#define MARGIN_F 0.5f

typedef short short8 __attribute__((ext_vector_type(8)));
typedef float floatx4 __attribute__((ext_vector_type(4)));

// RNE fp32 -> bf16 (inputs are finite; no NaN path needed)
__device__ inline unsigned short f2bf(float f) {
    unsigned int u = __float_as_uint(f);
    unsigned int r = (u + 0x7fffu + ((u >> 16) & 1u)) >> 16;
    return (unsigned short)r;
}

// ws layout (bytes):
//   [0, 4Mi)            embB  (Bn*Dn bf16)
//   [+0, +32Ki)         sq    (Bn f32)
//   [+32Ki, +64Ki)      posb  (Bn u32)
//   [+64Ki, +96Ki)      negb  (Bn u32)
//   [+96Ki, +96Ki+8)    tot, cnt (f32)
#define OFF_SQ   ((size_t)Bn * Dn * 2)
#define OFF_POS  (OFF_SQ + Bn * 4)
#define OFF_NEG  (OFF_POS + Bn * 4)
#define OFF_ACC  (OFF_NEG + Bn * 4)

// ---------------- prep: cast to bf16, sq[i], init reduction buffers ----------
__global__ __launch_bounds__(256) void prep_kernel(
        const float* __restrict__ emb, unsigned short* __restrict__ embB,
        float* __restrict__ sq, unsigned int* __restrict__ posb,
        unsigned int* __restrict__ negb, float* __restrict__ accs) {
    const int w = threadIdx.x >> 6;
    const int lane = threadIdx.x & 63;
    const int row = blockIdx.x * 4 + w;   // grid = Bn/4

    const float4 v = *(const float4*)(emb + (size_t)row * Dn + lane * 4);
    float ss = v.x * v.x + v.y * v.y + v.z * v.z + v.w * v.w;
    #pragma unroll
    for (int m = 32; m >= 1; m >>= 1) ss += __shfl_xor(ss, m);

    uint2 o;
    o.x = (unsigned int)f2bf(v.x) | ((unsigned int)f2bf(v.y) << 16);
    o.y = (unsigned int)f2bf(v.z) | ((unsigned int)f2bf(v.w) << 16);
    *(uint2*)(embB + (size_t)row * Dn + lane * 4) = o;

    if (lane == 0) {
        sq[row] = ss;
        posb[row] = 0u;            // sentinel: any real encoded score > 0
        negb[row] = 0xFFFFFFFFu;   // sentinel: any real encoded score smaller
    }
    if (blockIdx.x == 0 && threadIdx.x == 0) { accs[0] = 0.0f; accs[1] = 0.0f; }
}

// ---------------- mine: X·X^T via MFMA, pipelined staging, fused mining ------
// block = 256 thr (4 waves). Block tile: 128 i x 32 j per iter, 16 iters (512 j).
// Wave w: i in [iBase, iBase+32) as 2 m-subtiles of 16. grid = (64, 16).
__global__ __launch_bounds__(256, 4) void mine_kernel(
        const unsigned short* __restrict__ embB, const float* __restrict__ sq,
        const int* __restrict__ labels, unsigned int* __restrict__ posb,
        unsigned int* __restrict__ negb) {
    // pad 256 -> 264 shorts (132 dwords); rows 16B-aligned (528 B)
    __shared__ unsigned short sB[32][264];   // 16896 B

    const int tid  = threadIdx.x;
    const int w    = tid >> 6;
    const int lane = tid & 63;
    const int quad = lane >> 4;
    const int c    = lane & 15;

    const int iBase  = blockIdx.x * 128 + w * 32;
    const int jSplit = blockIdx.y * (Bn / 16);   // 512 j per block

    // A fragments in registers for the whole j-loop: 2 m-subtiles x 8 k-steps
    // A[m = lane&15][k = quad*8 + e], k-step stride 32
    short8 aFrag[2][8];
    #pragma unroll
    for (int m = 0; m < 2; ++m) {
        const unsigned short* ap = embB + (size_t)(iBase + m * 16 + c) * Dn + quad * 8;
        #pragma unroll
        for (int ks = 0; ks < 8; ++ks)
            aFrag[m][ks] = *(const short8*)(ap + ks * 32);
    }
    // labels of the rows this lane reduces (C/D rows: quad*4+r)
    int labI[2][4];
    #pragma unroll
    for (int m = 0; m < 2; ++m)
        #pragma unroll
        for (int r = 0; r < 4; ++r)
            labI[m][r] = labels[iBase + m * 16 + quad * 4 + r];

    float rpos[2][4], rneg[2][4];
    #pragma unroll
    for (int m = 0; m < 2; ++m)
        #pragma unroll
        for (int r = 0; r < 4; ++r) { rpos[m][r] = -1e30f; rneg[m][r] = 1e30f; }

    // prefetch tile 0 into registers (32 rows x 512 B = 4 uint4/thread)
    uint4 pf[4];
    #pragma unroll
    for (int it = 0; it < 4; ++it) {
        int g = it * 256 + tid, row = g >> 5, ch = g & 31;
        pf[it] = *(const uint4*)(embB + (size_t)(jSplit + row) * Dn + ch * 8);
    }
    int   nl0 = labels[jSplit + c],      nl1 = labels[jSplit + 16 + c];
    float ns0 = sq[jSplit + c],          ns1 = sq[jSplit + 16 + c];

    for (int jt = 0; jt < 16; ++jt) {
        const int jBase = jSplit + jt * 32;
        __syncthreads();            // previous compute done reading sB
        #pragma unroll
        for (int it = 0; it < 4; ++it) {
            int g = it * 256 + tid, row = g >> 5, ch = g & 31;
            *(uint4*)(&sB[row][ch * 8]) = pf[it];
        }
        const int   l0 = nl0, l1 = nl1;
        const float q0 = ns0, q1 = ns1;
        __syncthreads();
        if (jt < 15) {              // issue next tile's loads; waited next iter
            const int jn = jBase + 32;
            #pragma unroll
            for (int it = 0; it < 4; ++it) {
                int g = it * 256 + tid, row = g >> 5, ch = g & 31;
                pf[it] = *(const uint4*)(embB + (size_t)(jn + row) * Dn + ch * 8);
            }
            nl0 = labels[jn + c]; nl1 = labels[jn + 16 + c];
            ns0 = sq[jn + c];     ns1 = sq[jn + 16 + c];
        }
        #pragma unroll
        for (int n = 0; n < 2; ++n) {
            floatx4 acc0 = {0.f, 0.f, 0.f, 0.f};
            floatx4 acc1 = {0.f, 0.f, 0.f, 0.f};
            const unsigned short* bp = &sB[n * 16 + c][quad * 8];
            #pragma unroll
            for (int ks = 0; ks < 8; ++ks) {
                short8 bFrag = *(const short8*)(bp + ks * 32);
                acc0 = __builtin_amdgcn_mfma_f32_16x16x32_bf16(aFrag[0][ks], bFrag, acc0, 0, 0, 0);
                acc1 = __builtin_amdgcn_mfma_f32_16x16x32_bf16(aFrag[1][ks], bFrag, acc1, 0, 0, 0);
            }
            const float sj = n ? q1 : q0;
            const int   lj = n ? l1 : l0;
            // s = sq_j - 2*dot: monotone proxy for dist. Diagonal has the
            // provable MINIMUM s for its row -> safe inside positive-max.
            #pragma unroll
            for (int r = 0; r < 4; ++r) {
                float s0 = fmaf(-2.0f, acc0[r], sj);
                float s1 = fmaf(-2.0f, acc1[r], sj);
                bool e0 = (lj == labI[0][r]);
                bool e1 = (lj == labI[1][r]);
                rpos[0][r] = e0 ? fmaxf(rpos[0][r], s0) : rpos[0][r];
                rneg[0][r] = e0 ? rneg[0][r] : fminf(rneg[0][r], s0);
                rpos[1][r] = e1 ? fmaxf(rpos[1][r], s1) : rpos[1][r];
                rneg[1][r] = e1 ? rneg[1][r] : fminf(rneg[1][r], s1);
            }
        }
    }

    // reduce across the 16 c-lanes of each quad (masks 1,2,4,8 stay in-quad),
    // merge to global: encode s+4 in (2.9, 7.1) -> uint order == float order.
    #pragma unroll
    for (int m = 0; m < 2; ++m)
        #pragma unroll
        for (int r = 0; r < 4; ++r) {
            float p = rpos[m][r], q = rneg[m][r];
            #pragma unroll
            for (int msk = 1; msk <= 8; msk <<= 1) {
                p = fmaxf(p, __shfl_xor(p, msk));
                q = fminf(q, __shfl_xor(q, msk));
            }
            if (c == 0) {
                int ig = iBase + m * 16 + quad * 4 + r;
                if (p > -1e29f) atomicMax(&posb[ig], __float_as_uint(p + 4.0f));
                if (q <  1e29f) atomicMin(&negb[ig], __float_as_uint(q + 4.0f));
            }
        }
}

// ---------------- finalize stage A: 32 blocks, atomic partial sums -----------
__global__ __launch_bounds__(256) void finalize_a(
        const float* __restrict__ sq, const unsigned int* __restrict__ posb,
        const unsigned int* __restrict__ negb, float* __restrict__ accs) {
    const int i = blockIdx.x * 256 + threadIdx.x;   // one row per thread
    unsigned int pb = posb[i], nb = negb[i];
    bool hp = (pb != 0u);
    bool hn = (nb != 0xFFFFFFFFu);
    float si  = sq[i];
    float dap = sqrtf(fmaxf(si + (__uint_as_float(pb) - 4.0f), 0.0f));
    float dan = sqrtf(fmaxf(si + (__uint_as_float(nb) - 4.0f), 0.0f));
    bool valid = hp && hn && (dan < dap + MARGIN_F);
    float t = valid ? fmaxf(dap - dan + MARGIN_F, 0.0f) : 0.0f;
    float cc = valid ? 1.0f : 0.0f;
    #pragma unroll
    for (int m = 32; m >= 1; m >>= 1) {
        t  += __shfl_xor(t, m);
        cc += __shfl_xor(cc, m);
    }
    __shared__ float sT[4], sC[4];
    int w = threadIdx.x >> 6, lane = threadIdx.x & 63;
    if (lane == 0) { sT[w] = t; sC[w] = cc; }
    __syncthreads();
    if (threadIdx.x == 0) {
        atomicAdd(&accs[0], sT[0] + sT[1] + sT[2] + sT[3]);
        atomicAdd(&accs[1], sC[0] + sC[1] + sC[2] + sC[3]);
    }
}

// ---------------- finalize stage B: divide ----------------------------------
__global__ void finalize_b(const float* __restrict__ accs, float* __restrict__ out) {
    float cc = accs[1];
    out[0] = (cc > 0.0f) ? accs[0] / cc : 0.0f;
}

extern "C" void kernel_launch(void* const* d_in, const int* in_sizes, int n_in,
                              void* d_out, int out_size, void* d_ws, size_t ws_size,
                              hipStream_t stream) {
    const float* emb   = (const float*)d_in[0];
    const int*  labels = (const int*)d_in[1];
    float* out = (float*)d_out;

    char* ws = (char*)d_ws;
    unsigned short* embB = (unsigned short*)ws;
    float*        sqv  = (float*)(ws + OFF_SQ);
    unsigned int* posb = (unsigned int*)(ws + OFF_POS);
    unsigned int* negb = (unsigned int*)(ws + OFF_NEG);
    float*        accs = (float*)(ws + OFF_ACC);

    prep_kernel<<<Bn / 4, 256, 0, stream>>>(emb, embB, sqv, posb, negb, accs);
    mine_kernel<<<dim3(64, 16), 256, 0, stream>>>(embB, sqv, labels, posb, negb);
    finalize_a<<<Bn / 256, 256, 0, stream>>>(sqv, posb, negb, accs);
    finalize_b<<<1, 1, 0, stream>>>(accs, out);
}

// Round 3
// 134.065 us; speedup vs baseline: 1.1156x; 1.1156x over previous
//
#include <hip/hip_runtime.h>
#include <hip/hip_bf16.h>

#define Bn 8192
#define Dn 256
#define MARGIN_F 0.5f

typedef short short8 __attribute__((ext_vector_type(8)));
typedef float floatx4 __attribute__((ext_vector_type(4)));

// RNE fp32 -> bf16
__device__ inline unsigned short f2bf(float f) {
    unsigned int u = __float_as_uint(f);
    unsigned int r = (u + 0x7fffu + ((u >> 16) & 1u)) >> 16;
    return (unsigned short)r;
}

// ws layout:
#define OFF_SQ   ((size_t)Bn * Dn * 2)
#define OFF_POS  (OFF_SQ + Bn * 4)
#define OFF_NEG  (OFF_POS + Bn * 4)
#define OFF_ACC  (OFF_NEG + Bn * 4)   // accs[0]=total, accs[1]=count, accs[2]=ticket

// ---------------- prep: cast to bf16, sq[i], init buffers -------------------
__global__ __launch_bounds__(256) void prep_kernel(
        const float* __restrict__ emb, unsigned short* __restrict__ embB,
        float* __restrict__ sq, unsigned int* __restrict__ posb,
        unsigned int* __restrict__ negb, unsigned int* __restrict__ accs) {
    const int w = threadIdx.x >> 6;
    const int lane = threadIdx.x & 63;
    const int row = blockIdx.x * 4 + w;

    const float4 v = *(const float4*)(emb + (size_t)row * Dn + lane * 4);
    float ss = v.x * v.x + v.y * v.y + v.z * v.z + v.w * v.w;
    #pragma unroll
    for (int m = 32; m >= 1; m >>= 1) ss += __shfl_xor(ss, m);

    uint2 o;
    o.x = (unsigned int)f2bf(v.x) | ((unsigned int)f2bf(v.y) << 16);
    o.y = (unsigned int)f2bf(v.z) | ((unsigned int)f2bf(v.w) << 16);
    *(uint2*)(embB + (size_t)row * Dn + lane * 4) = o;

    if (lane == 0) {
        sq[row] = ss;
        posb[row] = 0u;            // sentinel: real encoded scores are > 0
        negb[row] = 0xFFFFFFFFu;   // sentinel: real encoded scores are smaller
    }
    if (blockIdx.x == 0 && threadIdx.x == 0) {
        accs[0] = 0u; accs[1] = 0u; accs[2] = 0u;   // bits of 0.0f / ticket
    }
}

// ---------------- mine: LDS-free MFMA X·X^T with fused semi-hard mining ------
// grid (32, 16), block 256 = 4 waves. Wave w: 64 i-rows (4 m-tiles of 16),
// i = blockIdx.x*256 + w*64 .. +64.  j-range: blockIdx.y*512 .. +512.
// A frags live in registers for the whole j-loop; B frags load DIRECTLY from
// global (L2-resident 4 MiB embB; quads of a wave cover contiguous 64 B per
// row). No LDS, no barriers — latency hidden by 8 waves/CU + ILP.
__global__ __launch_bounds__(256, 2) void mine_kernel(
        const unsigned short* __restrict__ embB, const float* __restrict__ sq,
        const int* __restrict__ labels, unsigned int* __restrict__ posb,
        unsigned int* __restrict__ negb) {
    const int tid  = threadIdx.x;
    const int w    = tid >> 6;
    const int lane = tid & 63;
    const int quad = lane >> 4;
    const int c    = lane & 15;

    const int iBase  = blockIdx.x * 256 + w * 64;
    const int jSplit = blockIdx.y * 512;

    // A[m-tile][kstep]: row = iBase + m*16 + c, k = quad*8 (+32 per kstep)
    short8 aFrag[4][8];
    #pragma unroll
    for (int m = 0; m < 4; ++m) {
        const unsigned short* ap = embB + (size_t)(iBase + m * 16 + c) * Dn + quad * 8;
        #pragma unroll
        for (int ks = 0; ks < 8; ++ks)
            aFrag[m][ks] = *(const short8*)(ap + ks * 32);
    }
    // labels of the rows this lane reduces (C/D rows: quad*4+r)
    int labI[4][4];
    #pragma unroll
    for (int m = 0; m < 4; ++m)
        #pragma unroll
        for (int r = 0; r < 4; ++r)
            labI[m][r] = labels[iBase + m * 16 + quad * 4 + r];

    float rpos[4][4], rneg[4][4];
    #pragma unroll
    for (int m = 0; m < 4; ++m)
        #pragma unroll
        for (int r = 0; r < 4; ++r) { rpos[m][r] = -1e30f; rneg[m][r] = 1e30f; }

    for (int jt = 0; jt < 16; ++jt) {
        #pragma unroll
        for (int n = 0; n < 2; ++n) {
            const int jRow = jSplit + jt * 32 + n * 16 + c;
            const unsigned short* bp = embB + (size_t)jRow * Dn + quad * 8;
            const float sj = sq[jRow];
            const int   lj = labels[jRow];
            floatx4 acc[4];
            #pragma unroll
            for (int m = 0; m < 4; ++m) acc[m] = (floatx4){0.f, 0.f, 0.f, 0.f};
            #pragma unroll
            for (int kc = 0; kc < 2; ++kc) {
                short8 bF[4];
                #pragma unroll
                for (int k4 = 0; k4 < 4; ++k4)
                    bF[k4] = *(const short8*)(bp + (kc * 4 + k4) * 32);
                #pragma unroll
                for (int k4 = 0; k4 < 4; ++k4)
                    #pragma unroll
                    for (int m = 0; m < 4; ++m)
                        acc[m] = __builtin_amdgcn_mfma_f32_16x16x32_bf16(
                            aFrag[m][kc * 4 + k4], bF[k4], acc[m], 0, 0, 0);
            }
            // s = sq_j - 2*dot: monotone proxy for dist. Diagonal has the
            // row-minimum s -> harmless inside the positive-max.
            #pragma unroll
            for (int m = 0; m < 4; ++m)
                #pragma unroll
                for (int r = 0; r < 4; ++r) {
                    float s = fmaf(-2.0f, acc[m][r], sj);
                    bool  e = (lj == labI[m][r]);
                    rpos[m][r] = e ? fmaxf(rpos[m][r], s) : rpos[m][r];
                    rneg[m][r] = e ? rneg[m][r] : fminf(rneg[m][r], s);
                }
        }
    }

    // reduce over the 16 c-lanes of each quad; merge: encode s+4 (>0) so
    // uint order == float order.
    #pragma unroll
    for (int m = 0; m < 4; ++m)
        #pragma unroll
        for (int r = 0; r < 4; ++r) {
            float p = rpos[m][r], q = rneg[m][r];
            #pragma unroll
            for (int msk = 1; msk <= 8; msk <<= 1) {
                p = fmaxf(p, __shfl_xor(p, msk));
                q = fminf(q, __shfl_xor(q, msk));
            }
            if (c == 0) {
                int ig = iBase + m * 16 + quad * 4 + r;
                if (p > -1e29f) atomicMax(&posb[ig], __float_as_uint(p + 4.0f));
                if (q <  1e29f) atomicMin(&negb[ig], __float_as_uint(q + 4.0f));
            }
        }
}

// ---------------- finalize: partial sums + last-block divide -----------------
__global__ __launch_bounds__(256) void finalize_kernel(
        const float* __restrict__ sq, const unsigned int* __restrict__ posb,
        const unsigned int* __restrict__ negb, float* __restrict__ accsF,
        unsigned int* __restrict__ accsU, float* __restrict__ out) {
    const int i = blockIdx.x * 256 + threadIdx.x;
    unsigned int pb = posb[i], nb = negb[i];
    bool hp = (pb != 0u);
    bool hn = (nb != 0xFFFFFFFFu);
    float si  = sq[i];
    float dap = sqrtf(fmaxf(si + (__uint_as_float(pb) - 4.0f), 0.0f));
    float dan = sqrtf(fmaxf(si + (__uint_as_float(nb) - 4.0f), 0.0f));
    bool valid = hp && hn && (dan < dap + MARGIN_F);
    float t  = valid ? fmaxf(dap - dan + MARGIN_F, 0.0f) : 0.0f;
    float cc = valid ? 1.0f : 0.0f;
    #pragma unroll
    for (int m = 32; m >= 1; m >>= 1) {
        t  += __shfl_xor(t, m);
        cc += __shfl_xor(cc, m);
    }
    __shared__ float sT[4], sC[4];
    int w = threadIdx.x >> 6, lane = threadIdx.x & 63;
    if (lane == 0) { sT[w] = t; sC[w] = cc; }
    __syncthreads();
    if (threadIdx.x == 0) {
        atomicAdd(&accsF[0], sT[0] + sT[1] + sT[2] + sT[3]);
        atomicAdd(&accsF[1], sC[0] + sC[1] + sC[2] + sC[3]);
        __threadfence();
        unsigned int ticket = atomicAdd(&accsU[2], 1u);
        if (ticket == gridDim.x - 1) {          // last block: all sums landed
            float tot = atomicAdd(&accsF[0], 0.0f);   // atomic read-back
            float cnt = atomicAdd(&accsF[1], 0.0f);
            out[0] = (cnt > 0.0f) ? tot / cnt : 0.0f;
        }
    }
}

extern "C" void kernel_launch(void* const* d_in, const int* in_sizes, int n_in,
                              void* d_out, int out_size, void* d_ws, size_t ws_size,
                              hipStream_t stream) {
    const float* emb   = (const float*)d_in[0];
    const int*  labels = (const int*)d_in[1];
    float* out = (float*)d_out;

    char* ws = (char*)d_ws;
    unsigned short* embB = (unsigned short*)ws;
    float*        sqv  = (float*)(ws + OFF_SQ);
    unsigned int* posb = (unsigned int*)(ws + OFF_POS);
    unsigned int* negb = (unsigned int*)(ws + OFF_NEG);
    float*        accsF = (float*)(ws + OFF_ACC);
    unsigned int* accsU = (unsigned int*)(ws + OFF_ACC);

    prep_kernel<<<Bn / 4, 256, 0, stream>>>(emb, embB, sqv, posb, negb, accsU);
    mine_kernel<<<dim3(32, 16), 256, 0, stream>>>(embB, sqv, labels, posb, negb);
    finalize_kernel<<<Bn / 256, 256, 0, stream>>>(sqv, posb, negb, accsF, accsU, out);
}

// Round 4
// 118.685 us; speedup vs baseline: 1.2602x; 1.1296x over previous
//
#include <hip/hip_runtime.h>
#include <hip/hip_bf16.h>

#define Bn 8192
#define Dn 256
#define MARGIN_F 0.5f

typedef short short8 __attribute__((ext_vector_type(8)));
typedef float floatx4 __attribute__((ext_vector_type(4)));

// RNE fp32 -> bf16
__device__ inline unsigned short f2bf(float f) {
    unsigned int u = __float_as_uint(f);
    unsigned int r = (u + 0x7fffu + ((u >> 16) & 1u)) >> 16;
    return (unsigned short)r;
}

// ws layout. embT is k-group-transposed: 16-B unit embT[(k>>3)*Bn + j] holds
// bf16 elements (k&~7)..(k|7) of row j. Fragment loads (quarter-wave = 16
// consecutive rows) are contiguous 256 B -> fully coalesced.
#define OFF_SQ   ((size_t)Bn * Dn * 2)
#define OFF_POS  (OFF_SQ + Bn * 4)
#define OFF_NEG  (OFF_POS + Bn * 4)
#define OFF_ACC  (OFF_NEG + Bn * 4)   // [0]=total f32, [1]=count f32, [2]=ticket u32

// ---------------- prep: bf16 cast + k-group transpose, sq[i], init ----------
__global__ __launch_bounds__(256) void prep_kernel(
        const float* __restrict__ emb, unsigned short* __restrict__ embT,
        float* __restrict__ sq, unsigned int* __restrict__ posb,
        unsigned int* __restrict__ negb, unsigned int* __restrict__ accs) {
    const int w = threadIdx.x >> 6;
    const int lane = threadIdx.x & 63;
    const int row = blockIdx.x * 4 + w;   // grid = Bn/4, one wave per row

    const float4 v = *(const float4*)(emb + (size_t)row * Dn + lane * 4);
    float ss = v.x * v.x + v.y * v.y + v.z * v.z + v.w * v.w;
    #pragma unroll
    for (int m = 32; m >= 1; m >>= 1) ss += __shfl_xor(ss, m);

    uint2 o;
    o.x = (unsigned int)f2bf(v.x) | ((unsigned int)f2bf(v.y) << 16);
    o.y = (unsigned int)f2bf(v.z) | ((unsigned int)f2bf(v.w) << 16);
    // lane holds k = 4*lane .. 4*lane+3 -> k-group lane>>1, half lane&1
    const int kg = lane >> 1;
    *(uint2*)(embT + ((size_t)kg * Bn + row) * 8 + (lane & 1) * 4) = o;

    if (lane == 0) {
        sq[row] = ss;
        posb[row] = 0u;            // sentinel: real encoded scores are > 0
        negb[row] = 0xFFFFFFFFu;   // sentinel: real encoded scores are smaller
    }
    if (blockIdx.x == 0 && threadIdx.x == 0) {
        accs[0] = 0u; accs[1] = 0u; accs[2] = 0u;
    }
}

// ---------------- mine: LDS-free MFMA X·X^T with fused semi-hard mining ------
// grid (32, 16), block 256 = 4 waves. Wave w: 64 i-rows (4 m-tiles of 16).
// A frags in registers for the whole j-loop; A and B frags both load from the
// k-group-transposed embT with coalesced quarter-wave-contiguous addresses.
__global__ __launch_bounds__(256, 2) void mine_kernel(
        const unsigned short* __restrict__ embT, const float* __restrict__ sq,
        const int* __restrict__ labels, unsigned int* __restrict__ posb,
        unsigned int* __restrict__ negb) {
    const int tid  = threadIdx.x;
    const int w    = tid >> 6;
    const int lane = tid & 63;
    const int quad = lane >> 4;
    const int c    = lane & 15;

    const int iBase  = blockIdx.x * 256 + w * 64;
    const int jSplit = blockIdx.y * 512;

    const size_t KS = (size_t)4 * Bn * 8;   // shorts per k-step (4 k-groups)

    // A[m-tile][kstep]: row = iBase+m*16+c, k = ks*32 + quad*8 + e
    short8 aFrag[4][8];
    #pragma unroll
    for (int m = 0; m < 4; ++m) {
        const unsigned short* ap = embT + ((size_t)quad * Bn + iBase + m * 16 + c) * 8;
        #pragma unroll
        for (int ks = 0; ks < 8; ++ks)
            aFrag[m][ks] = *(const short8*)(ap + ks * KS);
    }
    // labels of the rows this lane reduces (C/D rows: quad*4+r)
    int labI[4][4];
    #pragma unroll
    for (int m = 0; m < 4; ++m)
        #pragma unroll
        for (int r = 0; r < 4; ++r)
            labI[m][r] = labels[iBase + m * 16 + quad * 4 + r];

    float rpos[4][4], rneg[4][4];
    #pragma unroll
    for (int m = 0; m < 4; ++m)
        #pragma unroll
        for (int r = 0; r < 4; ++r) { rpos[m][r] = -1e30f; rneg[m][r] = 1e30f; }

    for (int jt = 0; jt < 16; ++jt) {
        #pragma unroll
        for (int n = 0; n < 2; ++n) {
            const int jRow = jSplit + jt * 32 + n * 16 + c;
            const unsigned short* bp = embT + ((size_t)quad * Bn + jRow) * 8;
            const float sj = sq[jRow];
            const int   lj = labels[jRow];
            floatx4 acc[4];
            #pragma unroll
            for (int m = 0; m < 4; ++m) acc[m] = (floatx4){0.f, 0.f, 0.f, 0.f};
            #pragma unroll
            for (int kc = 0; kc < 2; ++kc) {
                short8 bF[4];
                #pragma unroll
                for (int k4 = 0; k4 < 4; ++k4)
                    bF[k4] = *(const short8*)(bp + (kc * 4 + k4) * KS);
                #pragma unroll
                for (int k4 = 0; k4 < 4; ++k4)
                    #pragma unroll
                    for (int m = 0; m < 4; ++m)
                        acc[m] = __builtin_amdgcn_mfma_f32_16x16x32_bf16(
                            aFrag[m][kc * 4 + k4], bF[k4], acc[m], 0, 0, 0);
            }
            // s = sq_j - 2*dot: monotone proxy for dist. Diagonal is the
            // row-minimum s -> harmless inside the positive-max.
            #pragma unroll
            for (int m = 0; m < 4; ++m)
                #pragma unroll
                for (int r = 0; r < 4; ++r) {
                    float s = fmaf(-2.0f, acc[m][r], sj);
                    bool  e = (lj == labI[m][r]);
                    rpos[m][r] = e ? fmaxf(rpos[m][r], s) : rpos[m][r];
                    rneg[m][r] = e ? rneg[m][r] : fminf(rneg[m][r], s);
                }
        }
    }

    // reduce over the 16 c-lanes of each quad; encode s+4 (>0) so uint order
    // == float order; merge via atomics.
    #pragma unroll
    for (int m = 0; m < 4; ++m)
        #pragma unroll
        for (int r = 0; r < 4; ++r) {
            float p = rpos[m][r], q = rneg[m][r];
            #pragma unroll
            for (int msk = 1; msk <= 8; msk <<= 1) {
                p = fmaxf(p, __shfl_xor(p, msk));
                q = fminf(q, __shfl_xor(q, msk));
            }
            if (c == 0) {
                int ig = iBase + m * 16 + quad * 4 + r;
                if (p > -1e29f) atomicMax(&posb[ig], __float_as_uint(p + 4.0f));
                if (q <  1e29f) atomicMin(&negb[ig], __float_as_uint(q + 4.0f));
            }
        }
}

// ---------------- finalize: partial sums + last-block divide -----------------
__global__ __launch_bounds__(256) void finalize_kernel(
        const float* __restrict__ sq, const unsigned int* __restrict__ posb,
        const unsigned int* __restrict__ negb, float* __restrict__ accsF,
        unsigned int* __restrict__ accsU, float* __restrict__ out) {
    const int i = blockIdx.x * 256 + threadIdx.x;
    unsigned int pb = posb[i], nb = negb[i];
    bool hp = (pb != 0u);
    bool hn = (nb != 0xFFFFFFFFu);
    float si  = sq[i];
    float dap = sqrtf(fmaxf(si + (__uint_as_float(pb) - 4.0f), 0.0f));
    float dan = sqrtf(fmaxf(si + (__uint_as_float(nb) - 4.0f), 0.0f));
    bool valid = hp && hn && (dan < dap + MARGIN_F);
    float t  = valid ? fmaxf(dap - dan + MARGIN_F, 0.0f) : 0.0f;
    float cc = valid ? 1.0f : 0.0f;
    #pragma unroll
    for (int m = 32; m >= 1; m >>= 1) {
        t  += __shfl_xor(t, m);
        cc += __shfl_xor(cc, m);
    }
    __shared__ float sT[4], sC[4];
    int w = threadIdx.x >> 6, lane = threadIdx.x & 63;
    if (lane == 0) { sT[w] = t; sC[w] = cc; }
    __syncthreads();
    if (threadIdx.x == 0) {
        atomicAdd(&accsF[0], sT[0] + sT[1] + sT[2] + sT[3]);
        atomicAdd(&accsF[1], sC[0] + sC[1] + sC[2] + sC[3]);
        __threadfence();
        unsigned int ticket = atomicAdd(&accsU[2], 1u);
        if (ticket == gridDim.x - 1) {
            float tot = atomicAdd(&accsF[0], 0.0f);
            float cnt = atomicAdd(&accsF[1], 0.0f);
            out[0] = (cnt > 0.0f) ? tot / cnt : 0.0f;
        }
    }
}

extern "C" void kernel_launch(void* const* d_in, const int* in_sizes, int n_in,
                              void* d_out, int out_size, void* d_ws, size_t ws_size,
                              hipStream_t stream) {
    const float* emb   = (const float*)d_in[0];
    const int*  labels = (const int*)d_in[1];
    float* out = (float*)d_out;

    char* ws = (char*)d_ws;
    unsigned short* embT = (unsigned short*)ws;
    float*        sqv  = (float*)(ws + OFF_SQ);
    unsigned int* posb = (unsigned int*)(ws + OFF_POS);
    unsigned int* negb = (unsigned int*)(ws + OFF_NEG);
    float*        accsF = (float*)(ws + OFF_ACC);
    unsigned int* accsU = (unsigned int*)(ws + OFF_ACC);

    prep_kernel<<<Bn / 4, 256, 0, stream>>>(emb, embT, sqv, posb, negb, accsU);
    mine_kernel<<<dim3(32, 16), 256, 0, stream>>>(embT, sqv, labels, posb, negb);
    finalize_kernel<<<Bn / 256, 256, 0, stream>>>(sqv, posb, negb, accsF, accsU, out);
}